// Round 11
// baseline (108.696 us; speedup 1.0000x reference)
//
#include <hip/hip_runtime.h>
#include <hip/hip_fp16.h>
#include <math.h>

#define S 1024
#define D 64
#define BND 0.99999994f
#define FINF 3.4e38f
#define FMA4(acc,s,v) { (acc).x+=(s)*(v).x; (acc).y+=(s)*(v).y; (acc).z+=(s)*(v).z; (acc).w+=(s)*(v).w; }

__device__ __forceinline__ float waveSum(float v){
  #pragma unroll
  for(int o=32;o>0;o>>=1) v += __shfl_xor(v,o,64);
  return v;
}
// 1024-thread packed 2-value reductions (16 waves, one barrier pair each).
__device__ __forceinline__ float2 blockSum1024_v2(float2 v, float* red){
  #pragma unroll
  for(int o=32;o>0;o>>=1){ v.x+=__shfl_xor(v.x,o,64); v.y+=__shfl_xor(v.y,o,64); }
  const int wid=threadIdx.x>>6;
  __syncthreads();
  if((threadIdx.x&63)==0){ red[wid*2]=v.x; red[wid*2+1]=v.y; }
  __syncthreads();
  float2 s={0.f,0.f};
  #pragma unroll
  for(int k=0;k<16;k++){ s.x+=red[k*2]; s.y+=red[k*2+1]; }
  return s;
}
__device__ __forceinline__ float2 blockMin1024_v2(float2 v, float* red){
  #pragma unroll
  for(int o=32;o>0;o>>=1){ v.x=fminf(v.x,__shfl_xor(v.x,o,64)); v.y=fminf(v.y,__shfl_xor(v.y,o,64)); }
  const int wid=threadIdx.x>>6;
  __syncthreads();
  if((threadIdx.x&63)==0){ red[wid*2]=v.x; red[wid*2+1]=v.y; }
  __syncthreads();
  float2 s={red[0],red[1]};
  #pragma unroll
  for(int k=1;k<16;k++){ s.x=fminf(s.x,red[k*2]); s.y=fminf(s.y,red[k*2+1]); }
  return s;
}
// geodesic distance from (dot, |y|^2, |x|^2, 1-|x|^2)
__device__ __forceinline__ float distF(float dot, float y2, float x2, float B){
  const float A=1.f-2.f*dot+y2;
  const float den=fmaxf(1.f-2.f*dot+x2*y2,1e-15f);
  const float num2=fmaxf(A*A*x2 + B*B*y2 - 2.f*A*B*dot, 0.f);
  const float nn=sqrtf(num2/(den*den)+1e-15f);
  return 2.f*atanhf(fminf(nn,BND));
}

// K1: projections, expmap0(q/k), norms, v_r init, kT fp32 transpose, kTp fp16 d-pair
// transpose, combined vk=[vproj|kproj]
__global__ __launch_bounds__(64) void k_proj(
  const float* __restrict__ qin, const float* __restrict__ kin, const float* __restrict__ vin,
  const float* __restrict__ Wq, const float* __restrict__ bq,
  const float* __restrict__ Wk, const float* __restrict__ bk,
  const float* __restrict__ Wv, const float* __restrict__ bv,
  const float* __restrict__ vrand,
  float* __restrict__ q_hyp, float* __restrict__ k_hyp, float* __restrict__ kT,
  __half* __restrict__ kTp, float* __restrict__ vk,
  float* __restrict__ q2, float* __restrict__ k2, float* __restrict__ v_r)
{
  const int i = blockIdx.x, d = threadIdx.x;
  __shared__ __align__(16) float lq[D], lk[D], lv[D];
  __shared__ __align__(16) float skh[D];
  lq[d]=qin[i*D+d]; lk[d]=kin[i*D+d]; lv[d]=vin[i*D+d];
  __syncthreads();
  float aq=bq[d], ak=bk[d], av=bv[d];
  const float4* wq4=(const float4*)(Wq + d*D);
  const float4* wk4=(const float4*)(Wk + d*D);
  const float4* wv4=(const float4*)(Wv + d*D);
  #pragma unroll
  for(int e=0;e<16;e++){
    float4 a=wq4[e], b=wk4[e], c=wv4[e];
    aq += lq[4*e]*a.x + lq[4*e+1]*a.y + lq[4*e+2]*a.z + lq[4*e+3]*a.w;
    ak += lk[4*e]*b.x + lk[4*e+1]*b.y + lk[4*e+2]*b.z + lk[4*e+3]*b.w;
    av += lv[4*e]*c.x + lv[4*e+1]*c.y + lv[4*e+2]*c.z + lv[4*e+3]*c.w;
  }
  float nq = sqrtf(waveSum(aq*aq)+1e-15f);
  float qh = tanhf(nq)*aq/nq;
  q_hyp[i*D+d]=qh;
  float q2v = waveSum(qh*qh);
  if(d==0) q2[i]=q2v;
  float nk = sqrtf(waveSum(ak*ak)+1e-15f);
  float kh = tanhf(nk)*ak/nk;
  k_hyp[i*D+d]=kh;
  kT[(size_t)d*S + i]=kh;
  skh[d]=kh;
  float k2v = waveSum(kh*kh);
  if(d==0) k2[i]=k2v;
  vk[(size_t)i*128 + d]      = av;   // vproj half
  vk[(size_t)i*128 + 64 + d] = ak;   // kproj half
  float vr = vrand[i*D+d];
  float nn = sqrtf(waveSum(vr*vr));
  v_r[i*D+d] = vr/fmaxf(nn,1e-12f);
  __syncthreads();
  if(d<32){
    __half2 hp=__floats2half2_rn(skh[2*d], skh[2*d+1]);
    ((__half2*)kTp)[(size_t)d*S + i]=hp;   // [dp][j] half2 = (y[j][2dp], y[j][2dp+1])
  }
}

// K2 (weights+hcent): QB=2, 1024 threads, grid 512 (2 blocks/CU, 32 waves/CU).
//  P1: thread owns j=tid: dist->min->w->wsum->entropy
//  P2: h & centroid in ONE vk sweep + expmap0(centroid)
__global__ __launch_bounds__(1024,8) void k_wc(
  const float* __restrict__ q_hyp, const float* __restrict__ kT,
  const float* __restrict__ q2a, const float* __restrict__ k2a,
  const float* __restrict__ vk,
  float* __restrict__ wbuf, float* __restrict__ wsum, float* __restrict__ effm,
  float* __restrict__ h, float* __restrict__ c_hyp, float* __restrict__ c2)
{
  const int i0=blockIdx.x*2, tid=threadIdx.x;
  __shared__ __align__(16) float qv[2][D];
  __shared__ __align__(16) float wl[2][S];
  __shared__ __align__(16) float4 sA[2048];   // 32KB P2 partials
  __shared__ float red[32];
  if(tid<128) qv[tid>>6][tid&63]=q_hyp[i0*D+tid];
  __syncthreads();
  const float x20=q2a[i0], x21=q2a[i0+1];
  const float B0=1.f-x20, B1=1.f-x21;
  const int j=tid;
  // ---- P1: full dots, 1 j per thread ----
  float t0=0.f, t1=0.f;
  #pragma unroll 8
  for(int d=0;d<64;++d){
    const float y=kT[(size_t)d*S + j];
    t0+=y*qv[0][d]; t1+=y*qv[1][d];
  }
  const float y2=k2a[j];
  const float ds0=distF(t0,y2,x20,B0);
  const float ds1=distF(t1,y2,x21,B1);
  float2 mn2={ds0,ds1};
  mn2=blockMin1024_v2(mn2,red);
  const float w0=expf(mn2.x-ds0);
  const float w1=expf(mn2.y-ds1);
  wl[0][j]=w0; wl[1][j]=w1;
  wbuf[(size_t)i0*S+j]=w0; wbuf[(size_t)(i0+1)*S+j]=w1;
  float2 s2={w0,w1};
  s2=blockSum1024_v2(s2,red);          // also publishes wl
  const float s0=s2.x+1e-8f, s1=s2.y+1e-8f;
  if(tid==0){ wsum[i0]=s0; wsum[i0+1]=s1; }
  const float inv0=1.f/s0, inv1=1.f/s1;
  float2 e2;
  { const float p0=w0*inv0, p1=w1*inv1;
    e2.x = -p0*logf(p0+1e-8f);
    e2.y = -p1*logf(p1+1e-8f); }
  e2=blockSum1024_v2(e2,red);
  if(tid==0){ effm[i0]=expf(e2.x); effm[i0+1]=expf(e2.y); }
  // ---- P2: h + centroid in ONE vk sweep ----
  const int dq5=tid&31, g=tid>>5;      // 32 groups x 32-float4-wide rows
  float* const pA=(float*)sA;
  {
    float4 a0={0,0,0,0}, a1={0,0,0,0};
    #pragma unroll 4
    for(int jj=0;jj<32;jj++){
      const int j2=jj*32+g;
      const float4 y=((const float4*)(vk + (size_t)j2*128))[dq5];
      const float u0=wl[0][j2], u1=wl[1][j2];
      FMA4(a0,u0,y); FMA4(a1,u1,y);
    }
    *(float4*)&pA[(g*2+0)*128 + dq5*4]=a0;
    *(float4*)&pA[(g*2+1)*128 + dq5*4]=a1;
  }
  __syncthreads();
  if(tid<256){
    const int q=tid>>7, dd=tid&127;    // dd<64: h (wave-aligned), dd>=64: centroid
    float s=0.f;
    #pragma unroll 8
    for(int gg=0;gg<32;gg++) s+=pA[(gg*2+q)*128+dd];
    s *= (q ? inv1 : inv0);
    if(dd<64){
      h[(i0+q)*D+dd]=s;
    }else{
      const int d=dd-64;
      const float n=sqrtf(waveSum(s*s)+1e-15f);
      const float ch=tanhf(n)*s/n;
      c_hyp[(i0+q)*D+d]=ch;
      const float c2v=waveSum(ch*ch);
      if(d==0) c2[i0+q]=c2v;
    }
  }
}

// K3 (ab+power+final): QB=2, 1024 threads, grid 512.
//  PA: fp32 full-dot coefs + var; PB: 3 iters (pass1 fp16 full-dot, pass2 float4 k_hyp);
//  PC: bifurcation epilogue + out GEMV
__global__ __launch_bounds__(1024,8) void k_pmega(
  const float* __restrict__ c_hyp, const float* __restrict__ k_hyp,
  const float* __restrict__ kT, const __half* __restrict__ kTp,
  const float* __restrict__ c2a, const float* __restrict__ k2a,
  const float* __restrict__ wbuf, const float* __restrict__ wsum,
  const float* __restrict__ effm, const float* __restrict__ tau_p,
  const float* __restrict__ h, const float* __restrict__ q_hyp,
  const float* __restrict__ q2a, const float* __restrict__ v_r,
  const float* __restrict__ gu, const float* __restrict__ gamma_p,
  const float* __restrict__ ts_p, const float* __restrict__ Wo,
  const float* __restrict__ bo, float* __restrict__ out)
{
  const int i0=blockIdx.x*2, tid=threadIdx.x;
  __shared__ __align__(16) float cv[2][D];
  __shared__ __align__(16) float vv[2][D];
  __shared__ __align__(16) float aal[2][S];
  __shared__ __align__(16) float bbl[2][S];
  __shared__ __align__(16) float prow[2][S];
  __shared__ __align__(16) float4 sA[2048];   // 32KB pass2 partials
  __shared__ __align__(16) float fus[2][D];
  __shared__ float red[32];
  __shared__ float scd[2];
  float* const pA=(float*)sA;

  if(tid<128){
    const int q=tid>>6, d=tid&63;
    const float ch=c_hyp[i0*D+tid];
    const float vr=v_r[i0*D+tid];
    cv[q][d]=ch; vv[q][d]=vr;
    const float cd=waveSum(ch*vr);
    if(d==0) scd[q]=cd;
  }
  __syncthreads();
  const float x20=c2a[i0], x21=c2a[i0+1];
  const float Bc0=1.f-x20, Bc1=1.f-x21;
  const float mB0=fmaxf(Bc0,1e-15f), mB1=fmaxf(Bc1,1e-15f);
  const float inv0=1.f/wsum[i0], inv1=1.f/wsum[i0+1];
  const int j=tid;
  const int dq=tid&15, g=tid>>4;   // 64 groups for pass2
  const float tau=tau_p[0];

  // ---- PA: full-dot coefficients, 1 j per thread ----
  float2 var2;
  {
    float u0=0.f, u1=0.f;
    #pragma unroll 8
    for(int d=0;d<64;++d){
      const float y=kT[(size_t)d*S + j];
      u0+=y*cv[0][d]; u1+=y*cv[1][d];
    }
    const float y2=k2a[j];
    const float wq0=wbuf[(size_t)i0*S+j];
    const float wq1=wbuf[(size_t)(i0+1)*S+j];
    float var0, var1;
    {
      const float A=1.f-2.f*u0+y2;
      const float den=fmaxf(1.f-2.f*u0+x20*y2,1e-15f);
      const float num2=fmaxf(A*A*x20+Bc0*Bc0*y2-2.f*A*Bc0*u0,0.f);
      const float nn=sqrtf(num2/(den*den)+1e-15f);
      const float art=atanhf(fminf(nn,BND));
      var0 = wq0*inv0*4.f*art*art;
      const float coef=sqrtf(wq0+1e-8f)*mB0*art/(nn*den);
      aal[0][j]=-coef*A; bbl[0][j]=coef*Bc0;
    }
    {
      const float A=1.f-2.f*u1+y2;
      const float den=fmaxf(1.f-2.f*u1+x21*y2,1e-15f);
      const float num2=fmaxf(A*A*x21+Bc1*Bc1*y2-2.f*A*Bc1*u1,0.f);
      const float nn=sqrtf(num2/(den*den)+1e-15f);
      const float art=atanhf(fminf(nn,BND));
      var1 = wq1*inv1*4.f*art*art;
      const float coef=sqrtf(wq1+1e-8f)*mB1*art/(nn*den);
      aal[1][j]=-coef*A; bbl[1][j]=coef*Bc1;
    }
    float2 v2={var0,var1};
    var2=blockSum1024_v2(v2,red);   // also publishes aal/bbl
  }

  // ---- PB: 3 power iterations ----
  float2 sal2;
  for(int it3=0; it3<3; ++it3){
    // pass 1: fp16 full dot, 1 j per thread
    float t0=0.f, t1=0.f;
    #pragma unroll 8
    for(int dp=0;dp<32;++dp){
      const __half2 hy=((const __half2*)kTp)[(size_t)dp*S + j];
      const float2 f=__half22float2(hy);
      const float2 v0=*(const float2*)&vv[0][2*dp];
      const float2 v1=*(const float2*)&vv[1][2*dp];
      t0 += f.x*v0.x + f.y*v0.y;
      t1 += f.x*v1.x + f.y*v1.y;
    }
    {
      const float cd0=scd[0], cd1=scd[1];
      const float a0=aal[0][j], b0=bbl[0][j];
      const float a1=aal[1][j], b1=bbl[1][j];
      const float p0=a0*cd0+b0*t0;
      const float p1=a1*cd1+b1*t1;
      prow[0][j]=p0*b0;
      prow[1][j]=p1*b1;
      float2 s={p0*a0, p1*a1};
      sal2=blockSum1024_v2(s,red);   // also publishes prow
    }
    // pass 2: coalesced k_hyp sweep (64 groups x 16 j)
    {
      float4 a0={0,0,0,0}, a1={0,0,0,0};
      #pragma unroll 4
      for(int jj=0;jj<16;jj++){
        const int j2=jj*64+g;
        const float4 y=((const float4*)(k_hyp + j2*D))[dq];
        const float u0=prow[0][j2], u1=prow[1][j2];
        FMA4(a0,u0,y); FMA4(a1,u1,y);
      }
      *(float4*)&pA[(g*2+0)*64+dq*4]=a0;
      *(float4*)&pA[(g*2+1)*64+dq*4]=a1;
    }
    __syncthreads();
    // vv-combine + next cdot
    if(tid<128){
      const int q=tid>>6, d=tid&63;
      float od=(q?sal2.y:sal2.x)*cv[q][d];
      #pragma unroll 8
      for(int gg=0;gg<64;gg++) od += pA[(gg*2+q)*64+d];
      const float nn=sqrtf(waveSum(od*od));
      const float vn=od/fmaxf(nn,1e-12f);
      vv[q][d]=vn;
      const float cd=waveSum(cv[q][d]*vn);
      if(d==0) scd[q]=cd;
    }
    __syncthreads();
  }

  // ---- PC: epilogue + out GEMV ----
  if(tid<128){
    const int q=tid>>6, d=tid&63;
    const int i=i0+q;
    const float vart = q ? var2.y : var2.x;
    const float tns = vart - tau*effm[i];
    const float x2q_c = q ? x21 : x20;
    const float vd=vv[q][d];
    const float hd=h[i*D+d];
    const float qd=q_hyp[i*D+d];
    const float q2=q2a[i];
    const float wpg=vd/fmaxf(1.f-x2q_c,1e-15f);
    const float nq=sqrtf(q2+1e-15f);
    const float qt=atanhf(fminf(nq,BND))*qd/nq;
    const float ncn=sqrtf(x2q_c+1e-15f);
    const float ct=atanhf(fminf(ncn,BND))*cv[q][d]/ncn;
    const float df=qt-ct;
    const float nd=sqrtf(waveSum(df*df));
    const float fb=df/fmaxf(nd,1e-8f);
    const float wp=(vart>1e-5f)?wpg:fb;
    const float hn=sqrtf(waveSum(hd*hd)+1e-15f);
    const float hc=asinhf(hn)*hd/(hn+1e-8f);
    const float x=waveSum(hc*wp);
    const float hmag=sqrtf(waveSum(hc*hc)+1e-15f);
    const float amp=(tns>0.f)? hmag*tanhf(tns) : 0.f;
    const float u0=gu[i*2], u1=gu[i*2+1];
    const float eg=(u0>=u1)?1.f:-1.f;
    const float dc=tanhf(eg*amp - x);
    const float hp=hc+dc*wp;
    const float hpn=sqrtf(waveSum(hp*hp)+1e-15f)+1e-8f;
    const float hpb=hp*(tanhf(hpn*ts_p[0])/hpn);
    const float n2=sqrtf(waveSum(hpb*hpb)+1e-15f);
    const float hyp=tanhf(n2)*hpb/n2;
    const float n3=sqrtf(waveSum(hyp*hyp)+1e-15f);
    const float bif=atanhf(fminf(n3,BND))*hyp/n3;
    const float gate=1.f/(1.f+expf(-gamma_p[0]));
    fus[q][d]=(1.f-gate)*hd + gate*bif;
  }
  __syncthreads();
  if(tid<128){
    const int q=tid>>6, d=tid&63;
    float acc=bo[d];
    const float4* wo4=(const float4*)(Wo + d*D);
    #pragma unroll
    for(int e=0;e<16;e++){
      float4 wv=wo4[e];
      acc += fus[q][4*e]*wv.x + fus[q][4*e+1]*wv.y + fus[q][4*e+2]*wv.z + fus[q][4*e+3]*wv.w;
    }
    out[(i0+q)*D+d]=acc;
  }
}

extern "C" void kernel_launch(void* const* d_in, const int* in_sizes, int n_in,
                              void* d_out, int out_size, void* d_ws, size_t ws_size,
                              hipStream_t stream)
{
  const float* qin=(const float*)d_in[0];
  const float* kin=(const float*)d_in[1];
  const float* vin=(const float*)d_in[2];
  const float* Wq=(const float*)d_in[3];
  const float* bq=(const float*)d_in[4];
  const float* Wk=(const float*)d_in[5];
  const float* bk=(const float*)d_in[6];
  const float* Wv=(const float*)d_in[7];
  const float* bv=(const float*)d_in[8];
  const float* Wo=(const float*)d_in[9];
  const float* bo=(const float*)d_in[10];
  const float* tau=(const float*)d_in[11];
  const float* gamma=(const float*)d_in[12];
  const float* tscale=(const float*)d_in[13];
  const float* gu=(const float*)d_in[14];
  const float* vrand=(const float*)d_in[15];
  float* out=(float*)d_out;

  float* p=(float*)d_ws;
  float* q_hyp=p; p+=S*D;
  float* k_hyp=p; p+=S*D;
  float* kT=p;    p+=S*D;
  float* vk=p;    p+=(size_t)S*128;
  float* v_r=p;   p+=S*D;
  float* h=p;     p+=S*D;
  float* c_hyp=p; p+=S*D;
  float* q2=p;   p+=S;
  float* k2=p;   p+=S;
  float* c2=p;   p+=S;
  float* wsum=p; p+=S;
  float* effm=p; p+=S;
  __half* kTp=(__half*)p; p+=(S*D)/2;
  float* wbuf=p; p+=(size_t)S*S;

  k_proj<<<S,64,0,stream>>>(qin,kin,vin,Wq,bq,Wk,bk,Wv,bv,vrand,
                            q_hyp,k_hyp,kT,kTp,vk,q2,k2,v_r);
  k_wc<<<S/2,1024,0,stream>>>(q_hyp,kT,q2,k2,vk,
                              wbuf,wsum,effm,h,c_hyp,c2);
  k_pmega<<<S/2,1024,0,stream>>>(c_hyp,k_hyp,kT,kTp,c2,k2,wbuf,wsum,effm,tau,
                                 h,q_hyp,q2,v_r,gu,gamma,tscale,Wo,bo,out);
}

// Round 12
// 79.497 us; speedup vs baseline: 1.3673x; 1.3673x over previous
//
#include <hip/hip_runtime.h>
#include <hip/hip_fp16.h>
#include <math.h>

#define S 1024
#define D 64
#define BND 0.99999994f
#define FINF 3.4e38f
#define C4(v,c) ((&(v).x)[c])
#define FMA4(acc,s,v) { (acc).x+=(s)*(v).x; (acc).y+=(s)*(v).y; (acc).z+=(s)*(v).z; (acc).w+=(s)*(v).w; }

__device__ __forceinline__ float waveSum(float v){
  #pragma unroll
  for(int o=32;o>0;o>>=1) v += __shfl_xor(v,o,64);
  return v;
}
__device__ __forceinline__ float waveMin(float v){
  #pragma unroll
  for(int o=32;o>0;o>>=1) v = fminf(v,__shfl_xor(v,o,64));
  return v;
}
// 512-thread block reductions (8 waves). Leading sync guards LDS reuse.
__device__ __forceinline__ float blockSum512(float v, float* red){
  float w = waveSum(v);
  int wid = threadIdx.x>>6;
  __syncthreads();
  if((threadIdx.x&63)==0) red[wid]=w;
  __syncthreads();
  float s=0.f;
  #pragma unroll
  for(int k=0;k<8;k++) s+=red[k];
  return s;
}
__device__ __forceinline__ float blockMin512(float v, float* red){
  float w = waveMin(v);
  int wid = threadIdx.x>>6;
  __syncthreads();
  if((threadIdx.x&63)==0) red[wid]=w;
  __syncthreads();
  float s=red[0];
  #pragma unroll
  for(int k=1;k<8;k++) s=fminf(s,red[k]);
  return s;
}
// unpack 4 halfs (uint2) -> float4
__device__ __forceinline__ float4 h4tof4(uint2 u){
  union { unsigned int ui; __half2 h; } a, b;
  a.ui=u.x; b.ui=u.y;
  const float2 fa=__half22float2(a.h);
  const float2 fb=__half22float2(b.h);
  float4 r; r.x=fa.x; r.y=fa.y; r.z=fb.x; r.w=fb.y;
  return r;
}

// K1: q/k/v projections, expmap0(q), expmap0(k), norms, v_r init,
// + fp32 transposed kT, fp16 transposed kTh [d][j], fp16 row-major khr [j][d]
__global__ __launch_bounds__(64) void k_proj(
  const float* __restrict__ qin, const float* __restrict__ kin, const float* __restrict__ vin,
  const float* __restrict__ Wq, const float* __restrict__ bq,
  const float* __restrict__ Wk, const float* __restrict__ bk,
  const float* __restrict__ Wv, const float* __restrict__ bv,
  const float* __restrict__ vrand,
  float* __restrict__ q_hyp, float* __restrict__ k_hyp, float* __restrict__ kT,
  __half* __restrict__ kTh, __half* __restrict__ khr,
  float* __restrict__ vproj, float* __restrict__ kproj,
  float* __restrict__ q2, float* __restrict__ k2, float* __restrict__ v_r)
{
  const int i = blockIdx.x, d = threadIdx.x;
  __shared__ __align__(16) float lq[D], lk[D], lv[D];
  lq[d]=qin[i*D+d]; lk[d]=kin[i*D+d]; lv[d]=vin[i*D+d];
  __syncthreads();
  float aq=bq[d], ak=bk[d], av=bv[d];
  const float4* wq4=(const float4*)(Wq + d*D);
  const float4* wk4=(const float4*)(Wk + d*D);
  const float4* wv4=(const float4*)(Wv + d*D);
  #pragma unroll
  for(int e=0;e<16;e++){
    float4 a=wq4[e], b=wk4[e], c=wv4[e];
    aq += lq[4*e]*a.x + lq[4*e+1]*a.y + lq[4*e+2]*a.z + lq[4*e+3]*a.w;
    ak += lk[4*e]*b.x + lk[4*e+1]*b.y + lk[4*e+2]*b.z + lk[4*e+3]*b.w;
    av += lv[4*e]*c.x + lv[4*e+1]*c.y + lv[4*e+2]*c.z + lv[4*e+3]*c.w;
  }
  float nq = sqrtf(waveSum(aq*aq)+1e-15f);
  float qh = tanhf(nq)*aq/nq;
  q_hyp[i*D+d]=qh;
  float q2v = waveSum(qh*qh);
  if(d==0) q2[i]=q2v;
  float nk = sqrtf(waveSum(ak*ak)+1e-15f);
  float kh = tanhf(nk)*ak/nk;
  k_hyp[i*D+d]=kh;
  kT[(size_t)d*S + i]=kh;
  const __half khh=__float2half(kh);
  kTh[(size_t)d*S + i]=khh;          // [d][j] fp16 (pass-1 operand)
  khr[(size_t)i*D + d]=khh;          // [j][d] fp16 (pass-2 operand)
  float k2v = waveSum(kh*kh);
  if(d==0) k2[i]=k2v;
  vproj[i*D+d]=av;
  kproj[i*D+d]=ak;
  float vr = vrand[i*D+d];
  float nn = sqrtf(waveSum(vr*vr));
  v_r[i*D+d] = vr/fmaxf(nn,1e-12f);
}

// K2 (fused weights+hcent): 2 queries/block, 512 threads.  (unchanged from 79 µs best)
__global__ __launch_bounds__(512,4) void k_wc(
  const float* __restrict__ q_hyp, const float* __restrict__ kT,
  const float* __restrict__ q2a, const float* __restrict__ k2a,
  const float* __restrict__ vproj, const float* __restrict__ kproj,
  float* __restrict__ wbuf, float* __restrict__ wsum, float* __restrict__ effm,
  float* __restrict__ h, float* __restrict__ c_hyp, float* __restrict__ c2)
{
  const int i0=blockIdx.x*2, tid=threadIdx.x;
  __shared__ __align__(16) float qv[2][D];
  __shared__ __align__(16) float wl[2][S];
  __shared__ __align__(16) float4 sA[1024];   // phase1 pjoin / phase2 parth
  __shared__ __align__(16) float4 sB[1024];   // phase2 partc
  __shared__ float red[8];
  if(tid<128) qv[tid>>6][tid&63]=q_hyp[i0*D+tid];
  __syncthreads();
  const float x20=q2a[i0], x21=q2a[i0+1];
  const float B0=1.f-x20, B1=1.f-x21;
  const int jf=tid&255, dh=tid>>8;
  const float4* kT4=(const float4*)kT;
  // ---- phase 1a: partial dots (coalesced) ----
  {
    float4 p0={0,0,0,0}, p1={0,0,0,0};
    #pragma unroll 8
    for(int dd=0; dd<32; ++dd){
      const int d=(dh<<5)+dd;
      const float4 y=kT4[d*256+jf];
      const float c0=qv[0][d], c1=qv[1][d];
      FMA4(p0,c0,y); FMA4(p1,c1,y);
    }
    sA[(dh*2+0)*256+jf]=p0;
    sA[(dh*2+1)*256+jf]=p1;
  }
  __syncthreads();
  // ---- phase 1b: dist + min (256 combine threads) ----
  float dist[2][4];
  float mn0=FINF, mn1=FINF;
  if(tid<256){
    const float4 qa=sA[jf], qb=sA[512+jf];
    const float4 ra=sA[256+jf], rb=sA[768+jf];
    const float4 y2v=((const float4*)k2a)[jf];
    #pragma unroll
    for(int c=0;c<4;c++){
      const float y2=C4(y2v,c);
      {
        const float dot=C4(qa,c)+C4(qb,c);
        const float A=1.f-2.f*dot+y2;
        const float den=fmaxf(1.f-2.f*dot+x20*y2,1e-15f);
        const float num2=fmaxf(A*A*x20 + B0*B0*y2 - 2.f*A*B0*dot, 0.f);
        const float nn=sqrtf(num2/(den*den)+1e-15f);
        dist[0][c]=2.f*atanhf(fminf(nn,BND));
        mn0=fminf(mn0,dist[0][c]);
      }
      {
        const float dot=C4(ra,c)+C4(rb,c);
        const float A=1.f-2.f*dot+y2;
        const float den=fmaxf(1.f-2.f*dot+x21*y2,1e-15f);
        const float num2=fmaxf(A*A*x21 + B1*B1*y2 - 2.f*A*B1*dot, 0.f);
        const float nn=sqrtf(num2/(den*den)+1e-15f);
        dist[1][c]=2.f*atanhf(fminf(nn,BND));
        mn1=fminf(mn1,dist[1][c]);
      }
    }
  }
  const float m0=blockMin512(mn0,red);
  const float m1=blockMin512(mn1,red);
  float s0=0.f, s1=0.f;
  float w0c[4], w1c[4];
  if(tid<256){
    #pragma unroll
    for(int c=0;c<4;c++){
      w0c[c]=expf(m0-dist[0][c]); s0+=w0c[c];
      w1c[c]=expf(m1-dist[1][c]); s1+=w1c[c];
    }
    float4 a={w0c[0],w0c[1],w0c[2],w0c[3]};
    float4 b={w1c[0],w1c[1],w1c[2],w1c[3]};
    ((float4*)&wl[0][0])[jf]=a;
    ((float4*)&wl[1][0])[jf]=b;
    ((float4*)(wbuf+(size_t)i0*S))[jf]=a;
    ((float4*)(wbuf+(size_t)(i0+1)*S))[jf]=b;
  }
  s0=blockSum512(s0,red)+1e-8f;
  s1=blockSum512(s1,red)+1e-8f;
  if(tid==0){ wsum[i0]=s0; wsum[i0+1]=s1; }
  const float inv0=1.f/s0, inv1=1.f/s1;
  float e0=0.f, e1=0.f;
  if(tid<256){
    #pragma unroll
    for(int c=0;c<4;c++){
      const float p0=w0c[c]*inv0; e0 -= p0*logf(p0+1e-8f);
      const float p1=w1c[c]*inv1; e1 -= p1*logf(p1+1e-8f);
    }
  }
  e0=blockSum512(e0,red);
  e1=blockSum512(e1,red);
  if(tid==0){ effm[i0]=expf(e0); effm[i0+1]=expf(e1); }
  // ---- phase 2: h + centroid (coalesced (dq,g) sweep; sA/sB reused) ----
  const int dq=tid&15, g=tid>>4;
  float4 ah0={0,0,0,0}, ah1={0,0,0,0}, ac0={0,0,0,0}, ac1={0,0,0,0};
  #pragma unroll 4
  for(int jj=0;jj<32;jj++){
    const int j=jj*32+g;
    const float4 yv=((const float4*)(vproj + j*D))[dq];
    const float4 yk=((const float4*)(kproj + j*D))[dq];
    const float u0=wl[0][j], u1=wl[1][j];
    FMA4(ah0,u0,yv); FMA4(ah1,u1,yv);
    FMA4(ac0,u0,yk); FMA4(ac1,u1,yk);
  }
  float* pA=(float*)sA;
  float* pB=(float*)sB;
  *(float4*)&pA[(g*2+0)*64+dq*4]=ah0;
  *(float4*)&pA[(g*2+1)*64+dq*4]=ah1;
  *(float4*)&pB[(g*2+0)*64+dq*4]=ac0;
  *(float4*)&pB[(g*2+1)*64+dq*4]=ac1;
  __syncthreads();
  if(tid<128){
    const int q=tid>>6, d=tid&63;
    float hs=0.f, cs=0.f;
    #pragma unroll 8
    for(int gg=0;gg<32;gg++){ hs+=pA[(gg*2+q)*64+d]; cs+=pB[(gg*2+q)*64+d]; }
    const float invq = q ? inv1 : inv0;
    h[(i0+q)*D+d]=hs*invq;
    const float ca=cs*invq;
    const float n=sqrtf(waveSum(ca*ca)+1e-15f);
    const float ch=tanhf(n)*ca/n;
    c_hyp[(i0+q)*D+d]=ch;
    const float c2v=waveSum(ch*ch);
    if(d==0) c2[i0+q]=c2v;
  }
}

// K3 (fused ab+power+final): 2 queries/block, 512 threads.
//  PA fp32; PB: 3 iterations with fp16 K (pass1 kTh, pass2 khr); PC epilogue.
__global__ __launch_bounds__(512,4) void k_pmega(
  const float* __restrict__ c_hyp, const __half* __restrict__ khr,
  const float* __restrict__ kT, const __half* __restrict__ kTh,
  const float* __restrict__ c2a, const float* __restrict__ k2a,
  const float* __restrict__ wbuf, const float* __restrict__ wsum,
  const float* __restrict__ effm, const float* __restrict__ tau_p,
  const float* __restrict__ h, const float* __restrict__ q_hyp,
  const float* __restrict__ q2a, const float* __restrict__ v_r,
  const float* __restrict__ gu, const float* __restrict__ gamma_p,
  const float* __restrict__ ts_p, const float* __restrict__ Wo,
  const float* __restrict__ bo, float* __restrict__ out)
{
  const int i0=blockIdx.x*2, tid=threadIdx.x;
  __shared__ __align__(16) float cv[2][D];
  __shared__ __align__(16) float vv[2][D];
  __shared__ __align__(16) float aal[2][S];
  __shared__ __align__(16) float bbl[2][S];
  __shared__ __align__(16) float prow[2][S];
  __shared__ __align__(16) float4 sA[1024];   // pjoin / part alias (16KB)
  __shared__ __align__(16) float fus[2][D];
  __shared__ float red[8];
  __shared__ float scal[2][4];   // 0:var 1:tension 2:cdot

  if(tid<128){ cv[tid>>6][tid&63]=c_hyp[i0*D+tid]; vv[tid>>6][tid&63]=v_r[i0*D+tid]; }
  __syncthreads();
  const float x20=c2a[i0], x21=c2a[i0+1];
  const float Bc0=1.f-x20, Bc1=1.f-x21;
  const float mB0=fmaxf(Bc0,1e-15f), mB1=fmaxf(Bc1,1e-15f);
  const float inv0=1.f/wsum[i0], inv1=1.f/wsum[i0+1];
  const int jf=tid&255, dh=tid>>8;
  const float4* kT4=(const float4*)kT;
  const uint2* kTq=(const uint2*)kTh;   // [d][j] 4-half groups
  const uint2* khq=(const uint2*)khr;   // [j][d] 4-half groups

  // ---- phase A (fp32) ----
  {
    float4 p0={0,0,0,0}, p1={0,0,0,0};
    #pragma unroll 8
    for(int dd=0; dd<32; ++dd){
      const int d=(dh<<5)+dd;
      const float4 y=kT4[d*256+jf];
      const float c0=cv[0][d], c1=cv[1][d];
      FMA4(p0,c0,y); FMA4(p1,c1,y);
    }
    sA[(dh*2+0)*256+jf]=p0;
    sA[(dh*2+1)*256+jf]=p1;
  }
  __syncthreads();
  float var0p=0.f, var1p=0.f;
  if(tid<256){
    const float4 qa=sA[jf], qb=sA[512+jf];
    const float4 ra=sA[256+jf], rb=sA[768+jf];
    const float4 y2v=((const float4*)k2a)[jf];
    const float4 w0v=((const float4*)(wbuf+(size_t)i0*S))[jf];
    const float4 w1v=((const float4*)(wbuf+(size_t)(i0+1)*S))[jf];
    float a0c[4],b0c[4],a1c[4],b1c[4];
    #pragma unroll
    for(int c=0;c<4;c++){
      const float y2=C4(y2v,c);
      {
        const float dot=C4(qa,c)+C4(qb,c);
        const float A=1.f-2.f*dot+y2;
        const float den=fmaxf(1.f-2.f*dot+x20*y2,1e-15f);
        const float num2=fmaxf(A*A*x20+Bc0*Bc0*y2-2.f*A*Bc0*dot,0.f);
        const float nn=sqrtf(num2/(den*den)+1e-15f);
        const float art=atanhf(fminf(nn,BND));
        const float w=C4(w0v,c);
        var0p += w*inv0*4.f*art*art;
        const float coef=sqrtf(w+1e-8f)*mB0*art/(nn*den);
        a0c[c]=-coef*A; b0c[c]=coef*Bc0;
      }
      {
        const float dot=C4(ra,c)+C4(rb,c);
        const float A=1.f-2.f*dot+y2;
        const float den=fmaxf(1.f-2.f*dot+x21*y2,1e-15f);
        const float num2=fmaxf(A*A*x21+Bc1*Bc1*y2-2.f*A*Bc1*dot,0.f);
        const float nn=sqrtf(num2/(den*den)+1e-15f);
        const float art=atanhf(fminf(nn,BND));
        const float w=C4(w1v,c);
        var1p += w*inv1*4.f*art*art;
        const float coef=sqrtf(w+1e-8f)*mB1*art/(nn*den);
        a1c[c]=-coef*A; b1c[c]=coef*Bc1;
      }
    }
    { float4 t={a0c[0],a0c[1],a0c[2],a0c[3]}; ((float4*)&aal[0][0])[jf]=t; }
    { float4 t={a1c[0],a1c[1],a1c[2],a1c[3]}; ((float4*)&aal[1][0])[jf]=t; }
    { float4 t={b0c[0],b0c[1],b0c[2],b0c[3]}; ((float4*)&bbl[0][0])[jf]=t; }
    { float4 t={b1c[0],b1c[1],b1c[2],b1c[3]}; ((float4*)&bbl[1][0])[jf]=t; }
  }
  const float var0=blockSum512(var0p,red);
  const float var1=blockSum512(var1p,red);
  if(tid==0){
    scal[0][0]=var0; scal[0][1]=var0 - tau_p[0]*effm[i0];
    scal[1][0]=var1; scal[1][1]=var1 - tau_p[0]*effm[i0+1];
  }

  // ---- phase B: 3 power iterations (fp16 K) ----
  const int dq=tid&15, g=tid>>4;
  for(int it=0; it<3; ++it){
    __syncthreads();   // vv ready (and scal/ab on first pass)
    if(tid<128){
      const int q=tid>>6, d=tid&63;
      const float cd=waveSum(cv[q][d]*vv[q][d]);
      if(d==0) scal[q][2]=cd;
    }
    __syncthreads();
    const float cdot0=scal[0][2], cdot1=scal[1][2];
    // pass 1: transposed fp16 dots
    {
      float4 p0={0,0,0,0}, p1={0,0,0,0};
      #pragma unroll 8
      for(int dd=0; dd<32; ++dd){
        const int d=(dh<<5)+dd;
        const float4 y=h4tof4(kTq[d*256+jf]);
        const float c0=vv[0][d], c1=vv[1][d];
        FMA4(p0,c0,y); FMA4(p1,c1,y);
      }
      sA[(dh*2+0)*256+jf]=p0;
      sA[(dh*2+1)*256+jf]=p1;
    }
    __syncthreads();
    float sal0p=0.f, sal1p=0.f;
    if(tid<256){
      const float4 qa=sA[jf], qb=sA[512+jf];
      const float4 ra=sA[256+jf], rb=sA[768+jf];
      const float4 av0=((float4*)&aal[0][0])[jf];
      const float4 av1=((float4*)&aal[1][0])[jf];
      const float4 bv0=((float4*)&bbl[0][0])[jf];
      const float4 bv1=((float4*)&bbl[1][0])[jf];
      float pr0[4], pr1[4];
      #pragma unroll
      for(int c=0;c<4;c++){
        const float t0=C4(qa,c)+C4(qb,c);
        const float t1=C4(ra,c)+C4(rb,c);
        const float p0=C4(av0,c)*cdot0 + C4(bv0,c)*t0;
        const float p1=C4(av1,c)*cdot1 + C4(bv1,c)*t1;
        pr0[c]=p0*C4(bv0,c); sal0p += p0*C4(av0,c);
        pr1[c]=p1*C4(bv1,c); sal1p += p1*C4(av1,c);
      }
      { float4 t={pr0[0],pr0[1],pr0[2],pr0[3]}; ((float4*)&prow[0][0])[jf]=t; }
      { float4 t={pr1[0],pr1[1],pr1[2],pr1[3]}; ((float4*)&prow[1][0])[jf]=t; }
    }
    const float sal0=blockSum512(sal0p,red);
    const float sal1=blockSum512(sal1p,red);   // syncs also publish prow
    // pass 2: coalesced fp16 row-major sweep
    {
      float4 a0={0,0,0,0}, a1={0,0,0,0};
      #pragma unroll 4
      for(int jj=0;jj<32;jj++){
        const int j=jj*32+g;
        const float4 y=h4tof4(khq[j*16+dq]);
        const float u0=prow[0][j], u1=prow[1][j];
        FMA4(a0,u0,y); FMA4(a1,u1,y);
      }
      float* pA=(float*)sA;
      *(float4*)&pA[(g*2+0)*64+dq*4]=a0;
      *(float4*)&pA[(g*2+1)*64+dq*4]=a1;
    }
    __syncthreads();
    if(tid<128){
      const int q=tid>>6, d=tid&63;
      float* pA=(float*)sA;
      float od=(q?sal1:sal0)*cv[q][d];
      #pragma unroll 8
      for(int gg=0;gg<32;gg++) od += pA[(gg*2+q)*64+d];
      const float nn=sqrtf(waveSum(od*od));
      vv[q][d]=od/fmaxf(nn,1e-12f);
    }
  }
  __syncthreads();

  // ---- phase C: epilogue ----
  if(tid<128){
    const int q=tid>>6, d=tid&63;
    const int i=i0+q;
    const float x2q = q ? x21 : x20;
    const float vd=vv[q][d];
    const float vars=scal[q][0], tns=scal[q][1];
    const float hd=h[i*D+d];
    const float qd=q_hyp[i*D+d];
    const float q2=q2a[i];
    const float wpg=vd/fmaxf(1.f-x2q,1e-15f);
    const float nq=sqrtf(q2+1e-15f);
    const float qt=atanhf(fminf(nq,BND))*qd/nq;
    const float ncn=sqrtf(x2q+1e-15f);
    const float ct=atanhf(fminf(ncn,BND))*cv[q][d]/ncn;
    const float df=qt-ct;
    const float nd=sqrtf(waveSum(df*df));
    const float fb=df/fmaxf(nd,1e-8f);
    const float wp=(vars>1e-5f)?wpg:fb;
    const float hn=sqrtf(waveSum(hd*hd)+1e-15f);
    const float hc=asinhf(hn)*hd/(hn+1e-8f);
    const float x=waveSum(hc*wp);
    const float hmag=sqrtf(waveSum(hc*hc)+1e-15f);
    const float amp=(tns>0.f)? hmag*tanhf(tns) : 0.f;
    const float u0=gu[i*2], u1=gu[i*2+1];
    const float eg=(u0>=u1)?1.f:-1.f;
    const float dc=tanhf(eg*amp - x);
    const float hp=hc+dc*wp;
    const float hpn=sqrtf(waveSum(hp*hp)+1e-15f)+1e-8f;
    const float hpb=hp*(tanhf(hpn*ts_p[0])/hpn);
    const float n2=sqrtf(waveSum(hpb*hpb)+1e-15f);
    const float hyp=tanhf(n2)*hpb/n2;
    const float n3=sqrtf(waveSum(hyp*hyp)+1e-15f);
    const float bif=atanhf(fminf(n3,BND))*hyp/n3;
    const float gate=1.f/(1.f+expf(-gamma_p[0]));
    fus[q][d]=(1.f-gate)*hd + gate*bif;
  }
  __syncthreads();
  if(tid<128){
    const int q=tid>>6, d=tid&63;
    float acc=bo[d];
    const float4* wo4=(const float4*)(Wo + d*D);
    #pragma unroll
    for(int e=0;e<16;e++){
      float4 wv=wo4[e];
      acc += fus[q][4*e]*wv.x + fus[q][4*e+1]*wv.y + fus[q][4*e+2]*wv.z + fus[q][4*e+3]*wv.w;
    }
    out[(i0+q)*D+d]=acc;
  }
}

extern "C" void kernel_launch(void* const* d_in, const int* in_sizes, int n_in,
                              void* d_out, int out_size, void* d_ws, size_t ws_size,
                              hipStream_t stream)
{
  const float* qin=(const float*)d_in[0];
  const float* kin=(const float*)d_in[1];
  const float* vin=(const float*)d_in[2];
  const float* Wq=(const float*)d_in[3];
  const float* bq=(const float*)d_in[4];
  const float* Wk=(const float*)d_in[5];
  const float* bk=(const float*)d_in[6];
  const float* Wv=(const float*)d_in[7];
  const float* bv=(const float*)d_in[8];
  const float* Wo=(const float*)d_in[9];
  const float* bo=(const float*)d_in[10];
  const float* tau=(const float*)d_in[11];
  const float* gamma=(const float*)d_in[12];
  const float* tscale=(const float*)d_in[13];
  const float* gu=(const float*)d_in[14];
  const float* vrand=(const float*)d_in[15];
  float* out=(float*)d_out;

  float* p=(float*)d_ws;
  float* q_hyp=p; p+=S*D;
  float* k_hyp=p; p+=S*D;
  float* kT=p;    p+=S*D;
  float* vproj=p; p+=S*D;
  float* kproj=p; p+=S*D;
  float* v_r=p;   p+=S*D;
  float* h=p;     p+=S*D;
  float* c_hyp=p; p+=S*D;
  float* q2=p;   p+=S;
  float* k2=p;   p+=S;
  float* c2=p;   p+=S;
  float* wsum=p; p+=S;
  float* effm=p; p+=S;
  __half* kTh=(__half*)p; p+=(S*D)/2;
  __half* khr=(__half*)p; p+=(S*D)/2;
  float* wbuf=p; p+=(size_t)S*S;

  k_proj<<<S,64,0,stream>>>(qin,kin,vin,Wq,bq,Wk,bk,Wv,bv,vrand,
                            q_hyp,k_hyp,kT,kTh,khr,vproj,kproj,q2,k2,v_r);
  k_wc<<<S/2,512,0,stream>>>(q_hyp,kT,q2,k2,vproj,kproj,
                             wbuf,wsum,effm,h,c_hyp,c2);
  k_pmega<<<S/2,512,0,stream>>>(c_hyp,khr,kT,kTh,c2,k2,wbuf,wsum,effm,tau,
                                h,q_hyp,q2,v_r,gu,gamma,tscale,Wo,bo,out);
}